// Round 11
// baseline (161.648 us; speedup 1.0000x reference)
//
#include <hip/hip_runtime.h>
#include <hip/hip_bf16.h>
#include <stdint.h>

// Lorenz Euler integration: strictly serial recurrence over n_steps = T-1.
// One lane carries the (x,y,z) state; issue-bound on that single lane
// (wave64 VALU = 2 cy/instr, single-wave issue <= 1 instr/cy).
// Optimization: batch 4 rows (12 floats) into 3 float4 stores per group.
// 4000 rows = 1000 groups exactly: group 0 = init row + steps 1..3,
// groups 1..999 = 4 steps each.  3 + 999*4 = 3999 steps.  Store tuple
// registers double as the live state (no extra v_movs).

#define LORENZ_DT 0.01f

__global__ void lorenz_kernel(const float* __restrict__ sigma,
                              const float* __restrict__ rho,
                              const float* __restrict__ beta,
                              const float* __restrict__ stats,
                              float* __restrict__ out,
                              int n_t) {
    if (threadIdx.x != 0 || blockIdx.x != 0) return;

    const float s = sigma[0];
    const float r = rho[0];
    const float b = beta[0];

    const float dts = LORENZ_DT * s;        // DT*s
    const float cx  = 1.0f - dts;           // 1 - DT*s
    const float cy  = 1.0f - LORENZ_DT;     // 1 - DT
    const float cz  = 1.0f - LORENZ_DT * b; // 1 - DT*b

    float x = stats[0];
    float y = stats[1];
    float z = stats[2];

    // Same math/op-order as the verified round-3 kernel (absmax 3.9e-3).
#define LORENZ_STEP() do {                              \
        const float rz  = r - z;                        \
        const float dtx = LORENZ_DT * x;                \
        const float xy  = x * y;                        \
        const float nx = fmaf(dts, y, cx * x);          \
        const float ny = fmaf(dtx, rz, cy * y);         \
        const float nz = fmaf(LORENZ_DT, xy, cz * z);   \
        x = nx; y = ny; z = nz;                         \
    } while (0)

    const int n_steps = n_t - 1;

    if ((n_t & 3) == 0 && (((uintptr_t)out & 15u) == 0)) {
        // Fast path: rows come in groups of 4 = 3 aligned float4s.
        float4* p4 = (float4*)out;
        float4 A, B, C;
        // Group 0: row 0 = initial state, then steps 1..3.
        A.x = x; A.y = y; A.z = z;
        LORENZ_STEP(); A.w = x; B.x = y; B.y = z;
        LORENZ_STEP(); B.z = x; B.w = y; C.x = z;
        LORENZ_STEP(); C.y = x; C.z = y; C.w = z;
        p4[0] = A; p4[1] = B; p4[2] = C;
        p4 += 3;
        const int ngroups = n_t >> 2;  // 1000
        for (int g = 1; g < ngroups; ++g) {
            LORENZ_STEP(); A.x = x; A.y = y; A.z = z;
            LORENZ_STEP(); A.w = x; B.x = y; B.y = z;
            LORENZ_STEP(); B.z = x; B.w = y; C.x = z;
            LORENZ_STEP(); C.y = x; C.z = y; C.w = z;
            p4[0] = A; p4[1] = B; p4[2] = C;
            p4 += 3;
        }
    } else {
        // Generic fallback (any n_t).
        out[0] = x; out[1] = y; out[2] = z;
        float* p = out + 3;
        for (int i = 0; i < n_steps; ++i) {
            LORENZ_STEP();
            p[0] = x; p[1] = y; p[2] = z;
            p += 3;
        }
    }
#undef LORENZ_STEP
}

extern "C" void kernel_launch(void* const* d_in, const int* in_sizes, int n_in,
                              void* d_out, int out_size, void* d_ws, size_t ws_size,
                              hipStream_t stream) {
    const float* t     = (const float*)d_in[0];  // unused beyond its length
    const float* sigma = (const float*)d_in[1];
    const float* rho   = (const float*)d_in[2];
    const float* beta  = (const float*)d_in[3];
    const float* stats = (const float*)d_in[4];
    float* out = (float*)d_out;
    (void)t; (void)d_ws; (void)ws_size; (void)out_size;

    const int n_t = in_sizes[0];  // 4000 time points -> 3999 steps

    lorenz_kernel<<<1, 64, 0, stream>>>(sigma, rho, beta, stats, out, n_t);
}